// Round 1
// baseline (242.150 us; speedup 1.0000x reference)
//
#include <hip/hip_runtime.h>
#include <math.h>

#define BATCH 8
#define CH    256
#define H     128
#define W     128
#define OH    65
#define OW    65
#define STR   2
#define PAD   2
#define CGRP  32   // channels per thread in pool kernel

// Kernel 1: per-pixel channel L2 norm. n[b,h,w] = sqrt(sum_c x[b,c,h,w]^2)
__global__ __launch_bounds__(256) void norm_kernel(const float* __restrict__ x,
                                                   float* __restrict__ n) {
    int idx = blockIdx.x * blockDim.x + threadIdx.x;  // [0, BATCH*H*W)
    if (idx >= BATCH * H * W) return;
    int b = idx >> 14;          // / (H*W) = 16384
    int p = idx & 16383;
    const float* xp = x + (size_t)b * CH * H * W + p;
    float s = 0.f;
    #pragma unroll 8
    for (int c = 0; c < CH; ++c) {
        float v = xp[(size_t)c * (H * W)];
        s += v * v;
    }
    n[idx] = sqrtf(s);
}

// Kernel 2: softmax-weighted 3x3 stride-2 pooling.
__global__ __launch_bounds__(256) void pool_kernel(const float* __restrict__ x,
                                                   const float* __restrict__ n,
                                                   float* __restrict__ out) {
    int p = blockIdx.x * blockDim.x + threadIdx.x;  // output pixel within image
    if (p >= OH * OW) return;
    int b  = blockIdx.y;
    int cg = blockIdx.z;       // channel group of CGRP channels
    int oh = p / OW;
    int ow = p - oh * OW;

    const float* nb = n + b * (H * W);

    float nv[9];
    int   off[9];
    bool  val[9];
    float m = 0.0f;  // OOB positions carry n=0, so max starts at 0
    #pragma unroll
    for (int kh = 0; kh < 3; ++kh) {
        int ih = oh * STR + kh - PAD;
        bool vh = (unsigned)ih < (unsigned)H;
        #pragma unroll
        for (int kw = 0; kw < 3; ++kw) {
            int iw = ow * STR + kw - PAD;
            int k = kh * 3 + kw;
            bool v = vh && ((unsigned)iw < (unsigned)W);
            val[k] = v;
            off[k] = v ? (ih * W + iw) : 0;
            nv[k]  = v ? nb[off[k]] : 0.0f;
            m = fmaxf(m, nv[k]);
        }
    }

    float denom = 0.0f;
    float wts[9];
    #pragma unroll
    for (int k = 0; k < 9; ++k) {
        float e = __expf(nv[k] - m);   // OOB contributes exp(0-m) to denom
        denom += e;
        wts[k] = val[k] ? e : 0.0f;    // but weight 0 in numerator (x_pad = 0)
    }
    float inv = 1.0f / denom;
    #pragma unroll
    for (int k = 0; k < 9; ++k) wts[k] *= inv;

    const float* xb = x + (size_t)(b * CH + cg * CGRP) * (H * W);
    float*       ob = out + (size_t)(b * CH + cg * CGRP) * (OH * OW) + p;

    #pragma unroll 4
    for (int c = 0; c < CGRP; ++c) {
        const float* xc = xb + (size_t)c * (H * W);
        float acc = 0.f;
        #pragma unroll
        for (int k = 0; k < 9; ++k) acc += wts[k] * xc[off[k]];
        ob[(size_t)c * (OH * OW)] = acc;
    }
}

extern "C" void kernel_launch(void* const* d_in, const int* in_sizes, int n_in,
                              void* d_out, int out_size, void* d_ws, size_t ws_size,
                              hipStream_t stream) {
    const float* x = (const float*)d_in[0];
    float* out = (float*)d_out;
    float* nbuf = (float*)d_ws;  // BATCH*H*W floats = 512 KB

    int npix = BATCH * H * W;
    norm_kernel<<<(npix + 255) / 256, 256, 0, stream>>>(x, nbuf);

    dim3 grid((OH * OW + 255) / 256, BATCH, CH / CGRP);
    pool_kernel<<<grid, 256, 0, stream>>>(x, nbuf, out);
}

// Round 2
// 231.030 us; speedup vs baseline: 1.0481x; 1.0481x over previous
//
#include <hip/hip_runtime.h>
#include <math.h>

#define BATCH 8
#define CH    256
#define H     128
#define W     128
#define HW    (H * W)          // 16384
#define OH    65
#define OW    65
#define NPIX  (OH * OW)        // 4225
#define CGRP  32               // channels per thread in pool kernel

// Kernel 1: per-pixel channel L2 norm, float4-vectorized.
// Block = 256 threads = 4 waves. Block handles 256 consecutive pixels (64 float4-quads)
// of one image; wave wv sums channels [wv*64, wv*64+64); LDS-reduce the 4 partials.
__global__ __launch_bounds__(256) void norm_kernel(const float4* __restrict__ x4,
                                                   float4* __restrict__ n4) {
    __shared__ float4 part[4][64];
    const int lane = threadIdx.x & 63;
    const int wv   = threadIdx.x >> 6;
    const int q    = blockIdx.x * 64 + lane;   // global pixel-quad index
    const int b    = (q * 4) >> 14;            // / HW
    const int qin  = q - b * (HW / 4);         // quad within image

    const float4* p = x4 + (size_t)(b * CH + wv * 64) * (HW / 4) + qin;
    float4 acc = {0.f, 0.f, 0.f, 0.f};
    #pragma unroll 8
    for (int c = 0; c < 64; ++c) {
        float4 v = p[(size_t)c * (HW / 4)];
        acc.x += v.x * v.x; acc.y += v.y * v.y;
        acc.z += v.z * v.z; acc.w += v.w * v.w;
    }
    part[wv][lane] = acc;
    __syncthreads();
    if (wv == 0) {
        float4 a0 = part[0][lane], a1 = part[1][lane];
        float4 a2 = part[2][lane], a3 = part[3][lane];
        float4 r;
        r.x = sqrtf(a0.x + a1.x + a2.x + a3.x);
        r.y = sqrtf(a0.y + a1.y + a2.y + a3.y);
        r.z = sqrtf(a0.z + a1.z + a2.z + a3.z);
        r.w = sqrtf(a0.w + a1.w + a2.w + a3.w);
        n4[q] = r;
    }
}

// Kernel 2: softmax-weighted 3x3 stride-2 pooling.
// Per output pixel: window column base iw0 = 2*ow-2 is even -> aligned float2 covers
// kw=0,1 (contiguous, fully-used wave transaction); scalar covers kw=2. OOB positions
// get clamped (valid) addresses and exactly-zero weights.
__global__ __launch_bounds__(256) void pool_kernel(const float* __restrict__ x,
                                                   const float* __restrict__ n,
                                                   float* __restrict__ out) {
    int p = blockIdx.x * blockDim.x + threadIdx.x;
    if (p >= NPIX) return;
    const int b  = blockIdx.y;
    const int cg = blockIdx.z;
    const int oh = p / OW;
    const int ow = p - oh * OW;
    const int iw0 = ow * 2 - 2;

    const float* nb = n + b * HW;

    // softmax weights over the 9 window norms (OOB -> n=0 in denom, weight 0 in numer)
    float nv[9];
    bool  val[9];
    float m = 0.0f;
    #pragma unroll
    for (int kh = 0; kh < 3; ++kh) {
        int ih = oh * 2 + kh - 2;
        bool vh = (unsigned)ih < (unsigned)H;
        #pragma unroll
        for (int kw = 0; kw < 3; ++kw) {
            int iw = iw0 + kw;
            int k = kh * 3 + kw;
            bool v = vh && ((unsigned)iw < (unsigned)W);
            val[k] = v;
            nv[k]  = v ? nb[ih * W + iw] : 0.0f;
            m = fmaxf(m, nv[k]);
        }
    }
    float denom = 0.0f;
    float wts[9];
    #pragma unroll
    for (int k = 0; k < 9; ++k) {
        float e = __expf(nv[k] - m);
        denom += e;
        wts[k] = val[k] ? e : 0.0f;
    }
    float inv = 1.0f / denom;
    #pragma unroll
    for (int k = 0; k < 9; ++k) wts[k] *= inv;

    // clamped (always-valid) offsets; weight=0 kills OOB contributions
    int off2[3], offs[3];
    const int iwa = iw0 < 0 ? 0 : iw0;              // even -> float2 aligned
    const int iwc = (iw0 + 2) > (W - 1) ? (W - 1) : (iw0 + 2);
    #pragma unroll
    for (int r = 0; r < 3; ++r) {
        int ih = oh * 2 + r - 2;
        int ihc = ih < 0 ? 0 : (ih > H - 1 ? H - 1 : ih);
        off2[r] = ihc * W + iwa;
        offs[r] = ihc * W + iwc;
    }

    const float* xb = x + (size_t)(b * CH + cg * CGRP) * HW;
    float*       ob = out + (size_t)(b * CH + cg * CGRP) * NPIX + p;

    #pragma unroll 4
    for (int c = 0; c < CGRP; ++c) {
        const float* xc = xb + (size_t)c * HW;
        float acc = 0.f;
        #pragma unroll
        for (int r = 0; r < 3; ++r) {
            float2 v2 = *(const float2*)(xc + off2[r]);
            float  vs = xc[offs[r]];
            acc += wts[r * 3 + 0] * v2.x + wts[r * 3 + 1] * v2.y + wts[r * 3 + 2] * vs;
        }
        ob[(size_t)c * NPIX] = acc;
    }
}

extern "C" void kernel_launch(void* const* d_in, const int* in_sizes, int n_in,
                              void* d_out, int out_size, void* d_ws, size_t ws_size,
                              hipStream_t stream) {
    const float* x = (const float*)d_in[0];
    float* out = (float*)d_out;
    float* nbuf = (float*)d_ws;  // BATCH*H*W floats = 512 KB

    // K1: 32768 pixel-quads / 64 per block = 512 blocks
    norm_kernel<<<512, 256, 0, stream>>>((const float4*)x, (float4*)nbuf);

    dim3 grid((NPIX + 255) / 256, BATCH, CH / CGRP);
    pool_kernel<<<grid, 256, 0, stream>>>(x, nbuf, out);
}